// Round 4
// baseline (405.073 us; speedup 1.0000x reference)
//
#include <hip/hip_runtime.h>

typedef _Float16 h8 __attribute__((ext_vector_type(8)));
typedef float f4 __attribute__((ext_vector_type(4)));

#define MFMA16(a, b, c) __builtin_amdgcn_mfma_f32_16x16x32_f16((a), (b), (c), 0, 0, 0)

__device__ static inline void gl_lds16(const void* g, void* l) {
  __builtin_amdgcn_global_load_lds((const __attribute__((address_space(1))) unsigned int*)g,
                                   (__attribute__((address_space(3))) unsigned int*)l, 16, 0, 0);
}

// Monotone float<->uint encoding for atomicMax on floats (any sign).
__device__ static inline unsigned encf(float f) {
  unsigned u = __float_as_uint(f);
  return (u & 0x80000000u) ? ~u : (u | 0x80000000u);
}
__device__ static inline float decf(unsigned u) {
  return __uint_as_float((u & 0x80000000u) ? (u ^ 0x80000000u) : ~u);
}

// B=4, S=4096, D=512.
// IMG block = 16KB = 128 rows x 64 k fp16; half-offset(r,k) = r*64 + ((((k>>3)&7)^(r&7))<<3) + (k&7).
// XOR-8 swizzle baked in global so linear global_load_lds staging yields bank-floor ds_read_b128 frags.
//  Qimg/Kimg: block(b, rb=s>>7, kc=d>>6) at ((b*32+rb)*8+kc)*16KB        [16MB each]
//  VTimg:     block(b, rb=d>>7, kc=s>>6) at ((b*4+rb)*64+kc)*16KB        [16MB]
//  Wt:        block(z, rb=n>>7, kc=k>>6) at ((z*4+rb)*8+kc)*16KB         [1.5MB]
//  Simg(chunk): block(rbL, kc=t>>6) at (rbL*64+kc)*16KB, rbL = chunk-row>>7
// Softmax fused: qk atomically max-reduces rows into mEnc[]; pv exps A-tiles while
// staging and owns complete row-sums (K=4096 per block).
// Round-4: qk/pv K-loops restructured to counted-wait pipeline (T3-min):
//   vmcnt(0)+bar -> hoist ALL frag ds_reads -> lgkm(0)+bar -> STAGE(kt+1) -> MFMA.
//   Stage latency hides under own MFMA + TLP instead of draining at a __syncthreads.

// ---------------- weight convert (+ mEnc zero) ----------------
__global__ void wconv_kernel(const float* __restrict__ Wq, const float* __restrict__ Wk,
                             const float* __restrict__ Wv, _Float16* __restrict__ Wt,
                             unsigned* __restrict__ mEnc) {
  int idx = blockIdx.x * 256 + threadIdx.x;
  if (idx < 16384) mEnc[idx] = 0u;  // enc floor (< enc of any finite float)
  int z = idx >> 15, rem = idx & 32767;
  int n = rem >> 6, k0 = (rem & 63) << 3;
  const float* W = (z == 0) ? Wq : (z == 1) ? Wk : Wv;
  float sc = (z == 0) ? 0.5f : 1.0f;
  h8 v;
#pragma unroll
  for (int j = 0; j < 8; ++j) v[j] = (_Float16)(W[(k0 + j) * 512 + n] * sc);
  size_t blk = (size_t)((z * 4 + (n >> 7)) * 8 + (k0 >> 6));
  int off = (n & 127) * 64 + ((((k0 >> 3) & 7) ^ (n & 7)) << 3);
  *(h8*)&Wt[blk * 8192 + off] = v;
}

// ---------------- QKV projection -> images ----------------
__global__ __launch_bounds__(256, 3)
void proj_kernel(const float* __restrict__ x, const _Float16* __restrict__ Wt,
                 const float* __restrict__ bq, const float* __restrict__ bk,
                 const float* __restrict__ bv,
                 char* __restrict__ Qimg, char* __restrict__ Kimg, char* __restrict__ VTimg) {
  __shared__ _Float16 sMem[16384];  // sA 8192 + sB 8192; epilogue stash 16384
  _Float16* sA = sMem;
  _Float16* sB = sMem + 8192;
  const int tid = threadIdx.x;
  const int wave = tid >> 6, lane = tid & 63;
  const int quad = lane >> 4, lr = lane & 15;
  const int mbase = blockIdx.x * 128, nbase = blockIdx.y * 128, z = blockIdx.z;
  const int sr = tid >> 1, sseg = tid & 1;
  const int rbase = (wave & 1) * 64, cbase = (wave >> 1) * 64;
  const char* WtB = (const char*)Wt + ((size_t)(z * 4 + (nbase >> 7)) * 8) * 16384;

  float4 ax[8];
  f4 acc[4][4];
#pragma unroll
  for (int i = 0; i < 4; ++i)
#pragma unroll
    for (int j = 0; j < 4; ++j) { f4 zz = {0.f, 0.f, 0.f, 0.f}; acc[i][j] = zz; }

  {  // preload ax(0), stage B(0)
    const float4* asrc = (const float4*)&x[(size_t)(mbase + sr) * 512 + sseg * 32];
#pragma unroll
    for (int i = 0; i < 8; ++i) ax[i] = asrc[i];
#pragma unroll
    for (int j = 0; j < 4; ++j)
      gl_lds16(WtB + tid * 16 + j * 4096, (char*)sB + tid * 16 + j * 4096);
  }

  for (int kt = 0; kt < 8; ++kt) {
    if (kt > 0) __syncthreads();  // FREE: readers of kt-1 done
    // sA(kt) from ax (fp32->fp16, swizzled)
#pragma unroll
    for (int i = 0; i < 4; ++i) {
      h8 v;
      float4 f0 = ax[2 * i], f1 = ax[2 * i + 1];
      v[0] = (_Float16)f0.x; v[1] = (_Float16)f0.y; v[2] = (_Float16)f0.z; v[3] = (_Float16)f0.w;
      v[4] = (_Float16)f1.x; v[5] = (_Float16)f1.y; v[6] = (_Float16)f1.z; v[7] = (_Float16)f1.w;
      *(h8*)&sA[sr * 64 + (((sseg * 4 + i) ^ (sr & 7)) << 3)] = v;
    }
    if (kt > 0) {  // stage B(kt)
#pragma unroll
      for (int j = 0; j < 4; ++j)
        gl_lds16(WtB + kt * 16384 + tid * 16 + j * 4096, (char*)sB + tid * 16 + j * 4096);
    }
    __syncthreads();  // DRAIN
    if (kt < 7) {
      const float4* asrc = (const float4*)&x[(size_t)(mbase + sr) * 512 + (kt + 1) * 64 + sseg * 32];
#pragma unroll
      for (int i = 0; i < 8; ++i) ax[i] = asrc[i];
    }
#pragma unroll
    for (int ks = 0; ks < 2; ++ks) {
      h8 a[4], bb[4];
#pragma unroll
      for (int rt = 0; rt < 4; ++rt) {
        const int r = rbase + rt * 16 + lr;
        a[rt] = *(const h8*)&sA[r * 64 + ((((ks << 2) | quad) ^ (lr & 7)) << 3)];
      }
#pragma unroll
      for (int ct = 0; ct < 4; ++ct) {
        const int r = cbase + ct * 16 + lr;
        bb[ct] = *(const h8*)&sB[r * 64 + ((((ks << 2) | quad) ^ (lr & 7)) << 3)];
      }
#pragma unroll
      for (int rt = 0; rt < 4; ++rt)
#pragma unroll
        for (int ct = 0; ct < 4; ++ct)
          acc[rt][ct] = MFMA16(a[rt], bb[ct], acc[rt][ct]);
    }
  }

  // ---- epilogue: swizzled stash -> coalesced image stores ----
  const float* bias = (z == 0) ? bq : (z == 1) ? bk : bv;
  const float bscale = (z == 0) ? 0.5f : 1.0f;
  _Float16* sC = sMem;
  __syncthreads();
#pragma unroll
  for (int ct = 0; ct < 4; ++ct) {
    const int dl = cbase + ct * 16 + lr;
    const float bb = bias[nbase + dl] * bscale;
#pragma unroll
    for (int rt = 0; rt < 4; ++rt) {
#pragma unroll
      for (int r = 0; r < 4; ++r) {
        const int sl = rbase + rt * 16 + quad * 4 + r;
        const _Float16 val = (_Float16)(acc[rt][ct][r] + bb);
        if (z == 2) {  // VT: row=d, k=s
          sC[((sl >> 6) << 13) + dl * 64 + ((((sl >> 3) & 7) ^ (dl & 7)) << 3) + (sl & 7)] = val;
        } else {       // Q/K: row=s, k=d
          sC[((dl >> 6) << 13) + sl * 64 + ((((dl >> 3) & 7) ^ (sl & 7)) << 3) + (dl & 7)] = val;
        }
      }
    }
  }
  __syncthreads();
  const int b_ = mbase >> 12;
  char* dst;
  if (z != 2) {
    char* img = (z == 0) ? Qimg : Kimg;
    dst = img + ((size_t)((b_ * 32 + ((mbase & 4095) >> 7)) * 8 + (nbase >> 6) + (tid >> 7))) * 16384;
  } else {
    dst = VTimg + ((size_t)((b_ * 4 + (nbase >> 7)) * 64 + ((mbase & 4095) >> 6) + (tid >> 7))) * 16384;
  }
  dst += (size_t)(tid & 127) * 128;
#pragma unroll
  for (int k = 0; k < 8; ++k)
    *(int4*)(dst + k * 16) = *(const int4*)&sC[tid * 64 + k * 8];
}

// ---------------- QK GEMM: S[s][t] = Q . K^T -> Simg chunk (+ row-max atomics) ----------------
// Counted-wait pipeline: stage(kt+1) issued BEFORE MFMA cluster, drained at next loop top.
__global__ __launch_bounds__(256, 3)
void qk_kernel(const char* __restrict__ Qimg, const char* __restrict__ Kimg,
               char* __restrict__ S, unsigned* __restrict__ mEnc, int b0, int s0) {
  __shared__ _Float16 sMem[16384];
  _Float16* sA = sMem;
  _Float16* sB = sMem + 8192;
  const int tid = threadIdx.x;
  const int wave = tid >> 6, lane = tid & 63;
  const int quad = lane >> 4, lr = lane & 15;
  const int cb = blockIdx.x;                               // t-block 0..31
  const int rbL = blockIdx.z * gridDim.y + blockIdx.y;     // chunk row-block
  const int b = b0 + blockIdx.z;
  const int rbase = (wave & 1) * 64, cbase = (wave >> 1) * 64;
  const char* Ab = Qimg + ((size_t)((b * 32 + (s0 >> 7) + blockIdx.y) * 8)) * 16384;
  const char* Bb = Kimg + ((size_t)((b * 32 + cb) * 8)) * 16384;

  f4 acc[4][4];
#pragma unroll
  for (int i = 0; i < 4; ++i)
#pragma unroll
    for (int j = 0; j < 4; ++j) { f4 zz = {0.f, 0.f, 0.f, 0.f}; acc[i][j] = zz; }

#pragma unroll
  for (int j = 0; j < 4; ++j) {  // stage(0)
    gl_lds16(Ab + tid * 16 + j * 4096, (char*)sA + tid * 16 + j * 4096);
    gl_lds16(Bb + tid * 16 + j * 4096, (char*)sB + tid * 16 + j * 4096);
  }

  for (int kt = 0; kt < 8; ++kt) {
    // tile kt resident: own stage loads drained, all waves joined
    asm volatile("s_waitcnt vmcnt(0)" ::: "memory");
    __builtin_amdgcn_s_barrier();
    __builtin_amdgcn_sched_barrier(0);
    // hoist ALL fragment reads for this K-tile into registers
    h8 a[4][2], bb[4][2];
#pragma unroll
    for (int ks = 0; ks < 2; ++ks) {
#pragma unroll
      for (int rt = 0; rt < 4; ++rt) {
        const int r = rbase + rt * 16 + lr;
        a[rt][ks] = *(const h8*)&sA[r * 64 + ((((ks << 2) | quad) ^ (lr & 7)) << 3)];
      }
#pragma unroll
      for (int ct = 0; ct < 4; ++ct) {
        const int r = cbase + ct * 16 + lr;
        bb[ct][ks] = *(const h8*)&sB[r * 64 + ((((ks << 2) | quad) ^ (lr & 7)) << 3)];
      }
    }
    asm volatile("s_waitcnt lgkmcnt(0)" ::: "memory");
    __builtin_amdgcn_s_barrier();   // all waves' reads done -> LDS free
    __builtin_amdgcn_sched_barrier(0);
    if (kt < 7) {  // stage(kt+1): latency hides under MFMA below + TLP
#pragma unroll
      for (int j = 0; j < 4; ++j) {
        gl_lds16(Ab + (kt + 1) * 16384 + tid * 16 + j * 4096, (char*)sA + tid * 16 + j * 4096);
        gl_lds16(Bb + (kt + 1) * 16384 + tid * 16 + j * 4096, (char*)sB + tid * 16 + j * 4096);
      }
    }
    __builtin_amdgcn_s_setprio(1);
#pragma unroll
    for (int ks = 0; ks < 2; ++ks)
#pragma unroll
      for (int rt = 0; rt < 4; ++rt)
#pragma unroll
        for (int ct = 0; ct < 4; ++ct)
          acc[rt][ct] = MFMA16(a[rt][ks], bb[ct][ks], acc[rt][ct]);
    __builtin_amdgcn_s_setprio(0);
  }

  // ---- row-max partials over this block's 128 cols -> encoded atomicMax ----
  {
    const int growb = b * 4096 + s0 + blockIdx.y * 128;
#pragma unroll
    for (int rt = 0; rt < 4; ++rt) {
#pragma unroll
      for (int r = 0; r < 4; ++r) {
        float mx = fmaxf(fmaxf(acc[rt][0][r], acc[rt][1][r]),
                         fmaxf(acc[rt][2][r], acc[rt][3][r]));
        mx = fmaxf(mx, __shfl_xor(mx, 1));
        mx = fmaxf(mx, __shfl_xor(mx, 2));
        mx = fmaxf(mx, __shfl_xor(mx, 4));
        mx = fmaxf(mx, __shfl_xor(mx, 8));
        if (lr == 0)
          atomicMax(&mEnc[growb + rbase + rt * 16 + quad * 4 + r], encf(mx));
      }
    }
  }

  // epilogue: fp16 stash in Simg layout -> coalesced stores
  _Float16* sC = sMem;
  __syncthreads();
#pragma unroll
  for (int ct = 0; ct < 4; ++ct) {
    const int tl = cbase + ct * 16 + lr;
#pragma unroll
    for (int rt = 0; rt < 4; ++rt) {
#pragma unroll
      for (int r = 0; r < 4; ++r) {
        const int sl = rbase + rt * 16 + quad * 4 + r;
        sC[((tl >> 6) << 13) + sl * 64 + ((((tl >> 3) & 7) ^ (sl & 7)) << 3) + (tl & 7)] =
            (_Float16)acc[rt][ct][r];
      }
    }
  }
  __syncthreads();
  char* dst = S + ((size_t)(rbL * 64 + cb * 2 + (tid >> 7))) * 16384 + (size_t)(tid & 127) * 128;
#pragma unroll
  for (int k = 0; k < 8; ++k)
    *(int4*)(dst + k * 16) = *(const int4*)&sC[tid * 64 + k * 8];
}

// ---------------- PV GEMM with fused exp + rowsum: O = softmax(S) . V ----------------
// Counted-wait pipeline; A(kt+1) global loads issued early (regs), exp+ds_write+B-stage
// in the stage phase before the MFMA cluster. Each block owns full K=4096 -> local rowsums.
__global__ __launch_bounds__(256, 4)
void pv_kernel(const char* __restrict__ S, const char* __restrict__ VTimg,
               const unsigned* __restrict__ mEnc, float* __restrict__ out, int b0, int s0) {
  __shared__ _Float16 sMem[12288];  // sA 4096 (8KB) + sB 8192 (16KB)
  __shared__ float ls[64];          // per-row denominator
  _Float16* sA = sMem;
  _Float16* sB = sMem + 4096;
  const int tid = threadIdx.x;
  const int wave = tid >> 6, lane = tid & 63;
  const int quad = lane >> 4, lr = lane & 15;
  const int db = blockIdx.x;                            // 0..3
  const int sbL = blockIdx.z * gridDim.y + blockIdx.y;  // chunk 64-row block
  const int b = b0 + blockIdx.z;
  const int rbase = (wave & 1) * 32, cbase = (wave >> 1) * 64;
  const char* Ab = S + ((size_t)((sbL >> 1) * 64)) * 16384 + (size_t)(sbL & 1) * 8192;
  const char* Bb = VTimg + ((size_t)((b * 4 + db) * 64)) * 16384;

  // this thread's two staged rows (16B chunk at tid*16 -> row tid>>3; +4096B -> +32)
  const int lrow = tid >> 3;
  const int growb = b * 4096 + s0 + blockIdx.y * 64;
  const float m0 = decf(mEnc[growb + lrow]);
  const float m1 = decf(mEnc[growb + 32 + lrow]);
  float rs0 = 0.f, rs1 = 0.f;

  f4 acc[2][4];
#pragma unroll
  for (int i = 0; i < 2; ++i)
#pragma unroll
    for (int j = 0; j < 4; ++j) { f4 zz = {0.f, 0.f, 0.f, 0.f}; acc[i][j] = zz; }

  {  // prologue: B(0) gl_lds; A(0) direct h8 load -> exp -> sA
#pragma unroll
    for (int j = 0; j < 4; ++j)
      gl_lds16(Bb + tid * 16 + j * 4096, (char*)sB + tid * 16 + j * 4096);
    {
      h8 ha = *(const h8*)(Ab + tid * 16);
      h8 w;
#pragma unroll
      for (int u = 0; u < 8; ++u) { float e = __expf((float)ha[u] - m0); w[u] = (_Float16)e; rs0 += e; }
      *(h8*)((char*)sA + tid * 16) = w;
    }
    {
      h8 ha = *(const h8*)(Ab + tid * 16 + 4096);
      h8 w;
#pragma unroll
      for (int u = 0; u < 8; ++u) { float e = __expf((float)ha[u] - m1); w[u] = (_Float16)e; rs1 += e; }
      *(h8*)((char*)sA + tid * 16 + 4096) = w;
    }
  }

  for (int kt = 0; kt < 64; ++kt) {
    // tile kt resident: B gl_lds (vmcnt) + A ds_writes (lgkm) drained, waves joined
    asm volatile("s_waitcnt vmcnt(0) lgkmcnt(0)" ::: "memory");
    __builtin_amdgcn_s_barrier();
    __builtin_amdgcn_sched_barrier(0);
    // hoist ALL fragment reads into registers
    h8 a[2][2], bb[4][2];
#pragma unroll
    for (int ks = 0; ks < 2; ++ks) {
#pragma unroll
      for (int rt = 0; rt < 2; ++rt) {
        const int r = rbase + rt * 16 + lr;
        a[rt][ks] = *(const h8*)&sA[r * 64 + ((((ks << 2) | quad) ^ (lr & 7)) << 3)];
      }
#pragma unroll
      for (int ct = 0; ct < 4; ++ct) {
        const int r = cbase + ct * 16 + lr;
        bb[ct][ks] = *(const h8*)&sB[r * 64 + ((((ks << 2) | quad) ^ (lr & 7)) << 3)];
      }
    }
    // issue A(kt+1) global->reg loads early: latency spans the barrier + stage phase
    h8 ha0, ha1;
    if (kt < 63) {
      ha0 = *(const h8*)(Ab + (kt + 1) * 16384 + tid * 16);
      ha1 = *(const h8*)(Ab + (kt + 1) * 16384 + tid * 16 + 4096);
    }
    asm volatile("s_waitcnt lgkmcnt(0)" ::: "memory");
    __builtin_amdgcn_s_barrier();   // all waves' frag reads done -> LDS free
    __builtin_amdgcn_sched_barrier(0);
    if (kt < 63) {
#pragma unroll
      for (int j = 0; j < 4; ++j)
        gl_lds16(Bb + (kt + 1) * 16384 + tid * 16 + j * 4096, (char*)sB + tid * 16 + j * 4096);
      h8 w0, w1;
#pragma unroll
      for (int u = 0; u < 8; ++u) { float e = __expf((float)ha0[u] - m0); w0[u] = (_Float16)e; rs0 += e; }
#pragma unroll
      for (int u = 0; u < 8; ++u) { float e = __expf((float)ha1[u] - m1); w1[u] = (_Float16)e; rs1 += e; }
      *(h8*)((char*)sA + tid * 16) = w0;
      *(h8*)((char*)sA + tid * 16 + 4096) = w1;
    }
    __builtin_amdgcn_s_setprio(1);
#pragma unroll
    for (int ks = 0; ks < 2; ++ks)
#pragma unroll
      for (int rt = 0; rt < 2; ++rt)
#pragma unroll
        for (int ct = 0; ct < 4; ++ct)
          acc[rt][ct] = MFMA16(a[rt][ks], bb[ct][ks], acc[rt][ct]);
    __builtin_amdgcn_s_setprio(0);
  }

  // rowsum: reduce across the 8 threads sharing each staged row, publish via LDS
  rs0 += __shfl_xor(rs0, 1); rs0 += __shfl_xor(rs0, 2); rs0 += __shfl_xor(rs0, 4);
  rs1 += __shfl_xor(rs1, 1); rs1 += __shfl_xor(rs1, 2); rs1 += __shfl_xor(rs1, 4);
  if ((tid & 7) == 0) { ls[lrow] = rs0; ls[32 + lrow] = rs1; }
  __syncthreads();

  // epilogue: x 1/rowsum, scatter stores (64B segments per quad)
#pragma unroll
  for (int rt = 0; rt < 2; ++rt) {
#pragma unroll
    for (int r = 0; r < 4; ++r) {
      const int lrw = rbase + rt * 16 + quad * 4 + r;
      const int srow = s0 + blockIdx.y * 64 + lrw;
      const float li = 1.0f / ls[lrw];
      float* op = &out[((size_t)b * 4096 + srow) * 512 + db * 128];
#pragma unroll
      for (int ct = 0; ct < 4; ++ct)
        op[cbase + ct * 16 + lr] = acc[rt][ct][r] * li;
    }
  }
}

extern "C" void kernel_launch(void* const* d_in, const int* in_sizes, int n_in,
                              void* d_out, int out_size, void* d_ws, size_t ws_size,
                              hipStream_t stream) {
  (void)in_sizes; (void)n_in; (void)out_size;
  const float* x  = (const float*)d_in[0];
  const float* Wq = (const float*)d_in[1];
  const float* bq = (const float*)d_in[2];
  const float* Wk = (const float*)d_in[3];
  const float* bk = (const float*)d_in[4];
  const float* Wv = (const float*)d_in[5];
  const float* bv = (const float*)d_in[6];
  float* out = (float*)d_out;
  char* ws = (char*)d_ws;
  char* Qimg  = ws;
  char* Kimg  = ws + ((size_t)16 << 20);
  char* VTimg = ws + ((size_t)32 << 20);
  _Float16* Wt = (_Float16*)(ws + ((size_t)48 << 20));            // 1.5MB
  unsigned* mEnc = (unsigned*)(ws + ((size_t)50 << 20) - 65536);  // 64KB row-max
  char* Simg   = ws + ((size_t)50 << 20);

  wconv_kernel<<<dim3(384), dim3(256), 0, stream>>>(Wq, Wk, Wv, Wt, mEnc);
  proj_kernel<<<dim3(128, 4, 3), dim3(256), 0, stream>>>(x, Wt, bq, bk, bv, Qimg, Kimg, VTimg);

  // chunk ladder on ws_size (constant per deployment -> same work every call)
  const size_t avail = ws_size > ((size_t)50 << 20) ? ws_size - ((size_t)50 << 20) : 0;
  int nchunk, nb, Ms;
  if      (avail >= ((size_t)128 << 20)) { nchunk = 1;  nb = 4; Ms = 4096; }
  else if (avail >= ((size_t)64  << 20)) { nchunk = 2;  nb = 2; Ms = 4096; }
  else if (avail >= ((size_t)32  << 20)) { nchunk = 4;  nb = 1; Ms = 4096; }
  else if (avail >= ((size_t)16  << 20)) { nchunk = 8;  nb = 1; Ms = 2048; }
  else if (avail >= ((size_t)8   << 20)) { nchunk = 16; nb = 1; Ms = 1024; }
  else                                   { nchunk = 32; nb = 1; Ms = 512;  }
  const int chunksPerBatch = 4096 / Ms;  // for nb==1 paths; nb>1 has Ms=4096

  for (int c = 0; c < nchunk; ++c) {
    int b0, s0;
    if (nb > 1 || Ms == 4096) { b0 = c * nb; s0 = 0; }
    else { b0 = c / chunksPerBatch; s0 = (c % chunksPerBatch) * Ms; }
    qk_kernel<<<dim3(32, Ms / 128, nb), dim3(256), 0, stream>>>(Qimg, Kimg, Simg, mEnc, b0, s0);
    pv_kernel<<<dim3(4, Ms / 64, nb), dim3(256), 0, stream>>>(Simg, VTimg, mEnc, out, b0, s0);
  }
}

// Round 5
// 376.964 us; speedup vs baseline: 1.0746x; 1.0746x over previous
//
#include <hip/hip_runtime.h>

typedef _Float16 h8 __attribute__((ext_vector_type(8)));
typedef float f4 __attribute__((ext_vector_type(4)));

#define MFMA16(a, b, c) __builtin_amdgcn_mfma_f32_16x16x32_f16((a), (b), (c), 0, 0, 0)

__device__ static inline void gl_lds16(const void* g, void* l) {
  __builtin_amdgcn_global_load_lds((const __attribute__((address_space(1))) unsigned int*)g,
                                   (__attribute__((address_space(3))) unsigned int*)l, 16, 0, 0);
}

// Monotone float<->uint encoding for atomicMax on floats (any sign).
__device__ static inline unsigned encf(float f) {
  unsigned u = __float_as_uint(f);
  return (u & 0x80000000u) ? ~u : (u | 0x80000000u);
}
__device__ static inline float decf(unsigned u) {
  return __uint_as_float((u & 0x80000000u) ? (u ^ 0x80000000u) : ~u);
}

// B=4, S=4096, D=512.
// IMG block = 16KB = 128 rows x 64 k fp16; half-offset(r,k) = r*64 + ((((k>>3)&7)^(r&7))<<3) + (k&7).
// XOR-8 swizzle baked in global so linear global_load_lds staging yields bank-floor ds_read_b128 frags.
//  Qimg/Kimg: block(b, rb=s>>7, kc=d>>6) at ((b*32+rb)*8+kc)*16KB        [16MB each]
//  VTimg:     block(b, rb=d>>7, kc=s>>6) at ((b*4+rb)*64+kc)*16KB        [16MB]
//  Wt:        block(z, rb=n>>7, kc=k>>6) at ((z*4+rb)*8+kc)*16KB         [1.5MB]
//  Simg(chunk): block(rbL, kc=t>>6) at (rbL*64+kc)*16KB, rbL = chunk-row>>7
// Softmax fused: qk atomically max-reduces rows into mEnc[]; pv exps A-tiles while
// staging and owns complete row-sums (K=4096 per block).
// Round-5: pv merged over D (BN=512, one block per 64-row tile): S fetched once,
// exp'd once (was 4x each). 8 waves, dbuf LDS 145KB, 1 block/CU, grid=256.

// ---------------- weight convert (+ mEnc zero) ----------------
__global__ void wconv_kernel(const float* __restrict__ Wq, const float* __restrict__ Wk,
                             const float* __restrict__ Wv, _Float16* __restrict__ Wt,
                             unsigned* __restrict__ mEnc) {
  int idx = blockIdx.x * 256 + threadIdx.x;
  if (idx < 16384) mEnc[idx] = 0u;  // enc floor (< enc of any finite float)
  int z = idx >> 15, rem = idx & 32767;
  int n = rem >> 6, k0 = (rem & 63) << 3;
  const float* W = (z == 0) ? Wq : (z == 1) ? Wk : Wv;
  float sc = (z == 0) ? 0.5f : 1.0f;
  h8 v;
#pragma unroll
  for (int j = 0; j < 8; ++j) v[j] = (_Float16)(W[(k0 + j) * 512 + n] * sc);
  size_t blk = (size_t)((z * 4 + (n >> 7)) * 8 + (k0 >> 6));
  int off = (n & 127) * 64 + ((((k0 >> 3) & 7) ^ (n & 7)) << 3);
  *(h8*)&Wt[blk * 8192 + off] = v;
}

// ---------------- QKV projection -> images ----------------
__global__ __launch_bounds__(256, 3)
void proj_kernel(const float* __restrict__ x, const _Float16* __restrict__ Wt,
                 const float* __restrict__ bq, const float* __restrict__ bk,
                 const float* __restrict__ bv,
                 char* __restrict__ Qimg, char* __restrict__ Kimg, char* __restrict__ VTimg) {
  __shared__ _Float16 sMem[16384];  // sA 8192 + sB 8192; epilogue stash 16384
  _Float16* sA = sMem;
  _Float16* sB = sMem + 8192;
  const int tid = threadIdx.x;
  const int wave = tid >> 6, lane = tid & 63;
  const int quad = lane >> 4, lr = lane & 15;
  const int mbase = blockIdx.x * 128, nbase = blockIdx.y * 128, z = blockIdx.z;
  const int sr = tid >> 1, sseg = tid & 1;
  const int rbase = (wave & 1) * 64, cbase = (wave >> 1) * 64;
  const char* WtB = (const char*)Wt + ((size_t)(z * 4 + (nbase >> 7)) * 8) * 16384;

  float4 ax[8];
  f4 acc[4][4];
#pragma unroll
  for (int i = 0; i < 4; ++i)
#pragma unroll
    for (int j = 0; j < 4; ++j) { f4 zz = {0.f, 0.f, 0.f, 0.f}; acc[i][j] = zz; }

  {  // preload ax(0), stage B(0)
    const float4* asrc = (const float4*)&x[(size_t)(mbase + sr) * 512 + sseg * 32];
#pragma unroll
    for (int i = 0; i < 8; ++i) ax[i] = asrc[i];
#pragma unroll
    for (int j = 0; j < 4; ++j)
      gl_lds16(WtB + tid * 16 + j * 4096, (char*)sB + tid * 16 + j * 4096);
  }

  for (int kt = 0; kt < 8; ++kt) {
    if (kt > 0) __syncthreads();  // FREE: readers of kt-1 done
    // sA(kt) from ax (fp32->fp16, swizzled)
#pragma unroll
    for (int i = 0; i < 4; ++i) {
      h8 v;
      float4 f0 = ax[2 * i], f1 = ax[2 * i + 1];
      v[0] = (_Float16)f0.x; v[1] = (_Float16)f0.y; v[2] = (_Float16)f0.z; v[3] = (_Float16)f0.w;
      v[4] = (_Float16)f1.x; v[5] = (_Float16)f1.y; v[6] = (_Float16)f1.z; v[7] = (_Float16)f1.w;
      *(h8*)&sA[sr * 64 + (((sseg * 4 + i) ^ (sr & 7)) << 3)] = v;
    }
    if (kt > 0) {  // stage B(kt)
#pragma unroll
      for (int j = 0; j < 4; ++j)
        gl_lds16(WtB + kt * 16384 + tid * 16 + j * 4096, (char*)sB + tid * 16 + j * 4096);
    }
    __syncthreads();  // DRAIN
    if (kt < 7) {
      const float4* asrc = (const float4*)&x[(size_t)(mbase + sr) * 512 + (kt + 1) * 64 + sseg * 32];
#pragma unroll
      for (int i = 0; i < 8; ++i) ax[i] = asrc[i];
    }
#pragma unroll
    for (int ks = 0; ks < 2; ++ks) {
      h8 a[4], bb[4];
#pragma unroll
      for (int rt = 0; rt < 4; ++rt) {
        const int r = rbase + rt * 16 + lr;
        a[rt] = *(const h8*)&sA[r * 64 + ((((ks << 2) | quad) ^ (lr & 7)) << 3)];
      }
#pragma unroll
      for (int ct = 0; ct < 4; ++ct) {
        const int r = cbase + ct * 16 + lr;
        bb[ct] = *(const h8*)&sB[r * 64 + ((((ks << 2) | quad) ^ (lr & 7)) << 3)];
      }
#pragma unroll
      for (int rt = 0; rt < 4; ++rt)
#pragma unroll
        for (int ct = 0; ct < 4; ++ct)
          acc[rt][ct] = MFMA16(a[rt], bb[ct], acc[rt][ct]);
    }
  }

  // ---- epilogue: swizzled stash -> coalesced image stores ----
  const float* bias = (z == 0) ? bq : (z == 1) ? bk : bv;
  const float bscale = (z == 0) ? 0.5f : 1.0f;
  _Float16* sC = sMem;
  __syncthreads();
#pragma unroll
  for (int ct = 0; ct < 4; ++ct) {
    const int dl = cbase + ct * 16 + lr;
    const float bb = bias[nbase + dl] * bscale;
#pragma unroll
    for (int rt = 0; rt < 4; ++rt) {
#pragma unroll
      for (int r = 0; r < 4; ++r) {
        const int sl = rbase + rt * 16 + quad * 4 + r;
        const _Float16 val = (_Float16)(acc[rt][ct][r] + bb);
        if (z == 2) {  // VT: row=d, k=s
          sC[((sl >> 6) << 13) + dl * 64 + ((((sl >> 3) & 7) ^ (dl & 7)) << 3) + (sl & 7)] = val;
        } else {       // Q/K: row=s, k=d
          sC[((dl >> 6) << 13) + sl * 64 + ((((dl >> 3) & 7) ^ (sl & 7)) << 3) + (dl & 7)] = val;
        }
      }
    }
  }
  __syncthreads();
  const int b_ = mbase >> 12;
  char* dst;
  if (z != 2) {
    char* img = (z == 0) ? Qimg : Kimg;
    dst = img + ((size_t)((b_ * 32 + ((mbase & 4095) >> 7)) * 8 + (nbase >> 6) + (tid >> 7))) * 16384;
  } else {
    dst = VTimg + ((size_t)((b_ * 4 + (nbase >> 7)) * 64 + ((mbase & 4095) >> 6) + (tid >> 7))) * 16384;
  }
  dst += (size_t)(tid & 127) * 128;
#pragma unroll
  for (int k = 0; k < 8; ++k)
    *(int4*)(dst + k * 16) = *(const int4*)&sC[tid * 64 + k * 8];
}

// ---------------- QK GEMM: S[s][t] = Q . K^T -> Simg chunk (+ row-max atomics) ----------------
// Counted-wait pipeline: stage(kt+1) issued BEFORE MFMA cluster, drained at next loop top.
__global__ __launch_bounds__(256, 3)
void qk_kernel(const char* __restrict__ Qimg, const char* __restrict__ Kimg,
               char* __restrict__ S, unsigned* __restrict__ mEnc, int b0, int s0) {
  __shared__ _Float16 sMem[16384];
  _Float16* sA = sMem;
  _Float16* sB = sMem + 8192;
  const int tid = threadIdx.x;
  const int wave = tid >> 6, lane = tid & 63;
  const int quad = lane >> 4, lr = lane & 15;
  const int cb = blockIdx.x;                               // t-block 0..31
  const int rbL = blockIdx.z * gridDim.y + blockIdx.y;     // chunk row-block
  const int b = b0 + blockIdx.z;
  const int rbase = (wave & 1) * 64, cbase = (wave >> 1) * 64;
  const char* Ab = Qimg + ((size_t)((b * 32 + (s0 >> 7) + blockIdx.y) * 8)) * 16384;
  const char* Bb = Kimg + ((size_t)((b * 32 + cb) * 8)) * 16384;

  f4 acc[4][4];
#pragma unroll
  for (int i = 0; i < 4; ++i)
#pragma unroll
    for (int j = 0; j < 4; ++j) { f4 zz = {0.f, 0.f, 0.f, 0.f}; acc[i][j] = zz; }

#pragma unroll
  for (int j = 0; j < 4; ++j) {  // stage(0)
    gl_lds16(Ab + tid * 16 + j * 4096, (char*)sA + tid * 16 + j * 4096);
    gl_lds16(Bb + tid * 16 + j * 4096, (char*)sB + tid * 16 + j * 4096);
  }

  for (int kt = 0; kt < 8; ++kt) {
    // tile kt resident: own stage loads drained, all waves joined
    asm volatile("s_waitcnt vmcnt(0)" ::: "memory");
    __builtin_amdgcn_s_barrier();
    __builtin_amdgcn_sched_barrier(0);
    // hoist ALL fragment reads for this K-tile into registers
    h8 a[4][2], bb[4][2];
#pragma unroll
    for (int ks = 0; ks < 2; ++ks) {
#pragma unroll
      for (int rt = 0; rt < 4; ++rt) {
        const int r = rbase + rt * 16 + lr;
        a[rt][ks] = *(const h8*)&sA[r * 64 + ((((ks << 2) | quad) ^ (lr & 7)) << 3)];
      }
#pragma unroll
      for (int ct = 0; ct < 4; ++ct) {
        const int r = cbase + ct * 16 + lr;
        bb[ct][ks] = *(const h8*)&sB[r * 64 + ((((ks << 2) | quad) ^ (lr & 7)) << 3)];
      }
    }
    asm volatile("s_waitcnt lgkmcnt(0)" ::: "memory");
    __builtin_amdgcn_s_barrier();   // all waves' reads done -> LDS free
    __builtin_amdgcn_sched_barrier(0);
    if (kt < 7) {  // stage(kt+1): latency hides under MFMA below + TLP
#pragma unroll
      for (int j = 0; j < 4; ++j) {
        gl_lds16(Ab + (kt + 1) * 16384 + tid * 16 + j * 4096, (char*)sA + tid * 16 + j * 4096);
        gl_lds16(Bb + (kt + 1) * 16384 + tid * 16 + j * 4096, (char*)sB + tid * 16 + j * 4096);
      }
    }
    __builtin_amdgcn_s_setprio(1);
#pragma unroll
    for (int ks = 0; ks < 2; ++ks)
#pragma unroll
      for (int rt = 0; rt < 4; ++rt)
#pragma unroll
        for (int ct = 0; ct < 4; ++ct)
          acc[rt][ct] = MFMA16(a[rt][ks], bb[ct][ks], acc[rt][ct]);
    __builtin_amdgcn_s_setprio(0);
  }

  // ---- row-max partials over this block's 128 cols -> encoded atomicMax ----
  {
    const int growb = b * 4096 + s0 + blockIdx.y * 128;
#pragma unroll
    for (int rt = 0; rt < 4; ++rt) {
#pragma unroll
      for (int r = 0; r < 4; ++r) {
        float mx = fmaxf(fmaxf(acc[rt][0][r], acc[rt][1][r]),
                         fmaxf(acc[rt][2][r], acc[rt][3][r]));
        mx = fmaxf(mx, __shfl_xor(mx, 1));
        mx = fmaxf(mx, __shfl_xor(mx, 2));
        mx = fmaxf(mx, __shfl_xor(mx, 4));
        mx = fmaxf(mx, __shfl_xor(mx, 8));
        if (lr == 0)
          atomicMax(&mEnc[growb + rbase + rt * 16 + quad * 4 + r], encf(mx));
      }
    }
  }

  // epilogue: fp16 stash in Simg layout -> coalesced stores
  _Float16* sC = sMem;
  __syncthreads();
#pragma unroll
  for (int ct = 0; ct < 4; ++ct) {
    const int tl = cbase + ct * 16 + lr;
#pragma unroll
    for (int rt = 0; rt < 4; ++rt) {
#pragma unroll
      for (int r = 0; r < 4; ++r) {
        const int sl = rbase + rt * 16 + quad * 4 + r;
        sC[((tl >> 6) << 13) + sl * 64 + ((((tl >> 3) & 7) ^ (sl & 7)) << 3) + (tl & 7)] =
            (_Float16)acc[rt][ct][r];
      }
    }
  }
  __syncthreads();
  char* dst = S + ((size_t)(rbL * 64 + cb * 2 + (tid >> 7))) * 16384 + (size_t)(tid & 127) * 128;
#pragma unroll
  for (int k = 0; k < 8; ++k)
    *(int4*)(dst + k * 16) = *(const int4*)&sC[tid * 64 + k * 8];
}

// ---------------- PV GEMM, D-merged (BN=512): O[64 x 512] = softmax(S) . V ----------------
// One block per 64-row tile: S fetched ONCE, exp'd ONCE. 8 waves (2x4), per-wave 32x128.
// LDS: dbuf A (2x8KB) + dbuf B (2x64KB) = 145KB -> 1 block/CU, grid = 256 = #CUs.
// Counted single-barrier pipeline; B staged from VT (4MB/batch, XCD-L2 resident via swizzle).
__global__ __launch_bounds__(512, 2)
void pv_kernel(const char* __restrict__ S, const char* __restrict__ VTimg,
               const unsigned* __restrict__ mEnc, float* __restrict__ out,
               int b0, int s0, int nyb, int nb) {
  __shared__ _Float16 sMem[73728];  // sA0 @0, sA1 @4096, sB0 @8192, sB1 @40960 (elems)
  __shared__ float ls[64];
  const int tid = threadIdx.x;
  const int wave = tid >> 6, lane = tid & 63;
  const int quad = lane >> 4, lr = lane & 15;
  // block -> (batch, 64-row tile); nb==4: 2-XCDs-per-batch swizzle so VT L2-shares
  const int flat = blockIdx.x;
  int bL, yl;
  if (nb == 4) { bL = (flat & 7) >> 1; yl = ((flat >> 3) << 1) | (flat & 1); }
  else { bL = flat / nyb; yl = flat - bL * nyb; }
  const int b = b0 + bL;
  const int sbL = bL * nyb + yl;  // chunk-global 64-row block index
  const int rbase = (wave & 1) * 32, cbase = (wave >> 1) * 128;
  const char* Ab = S + ((size_t)((sbL >> 1) * 64)) * 16384 + (size_t)(sbL & 1) * 8192;
  const char* Bb = VTimg + ((size_t)(b * 4) * 64) * 16384;

  // this thread's staged A row (16B chunk at tid*16 -> row tid>>3)
  const int lrow = tid >> 3;
  const int growb = b * 4096 + s0 + yl * 64;
  const float m0 = decf(mEnc[growb + lrow]);
  float rs = 0.f;

  f4 acc[2][8];
#pragma unroll
  for (int i = 0; i < 2; ++i)
#pragma unroll
    for (int j = 0; j < 8; ++j) { f4 zz = {0.f, 0.f, 0.f, 0.f}; acc[i][j] = zz; }

  {  // prologue: stage tile 0 into buf 0
    h8 ha = *(const h8*)(Ab + tid * 16);
#pragma unroll
    for (int j = 0; j < 8; ++j)
      gl_lds16(Bb + (size_t)(j >> 1) * 1048576 + (j & 1) * 8192 + tid * 16,
               (char*)sMem + 16384 + j * 8192 + tid * 16);
    h8 w;
#pragma unroll
    for (int u = 0; u < 8; ++u) { float e = __expf((float)ha[u] - m0); w[u] = (_Float16)e; rs += e; }
    *(h8*)((char*)sMem + tid * 16) = w;
    asm volatile("s_waitcnt vmcnt(0) lgkmcnt(0)" ::: "memory");
    __builtin_amdgcn_s_barrier();
    __builtin_amdgcn_sched_barrier(0);
  }

  for (int kt = 0; kt < 64; ++kt) {
    const int cur = kt & 1;
    _Float16* sA = sMem + cur * 4096;
    _Float16* sB = sMem + 8192 + cur * 32768;
    char* sAn = (char*)sMem + (cur ^ 1) * 8192;
    char* sBn = (char*)sMem + 16384 + (cur ^ 1) * 65536;
    const bool more = (kt < 63);
    h8 han;
    if (more) {  // issue next-tile loads: A->reg first (so its wait leaves B in flight)
      han = *(const h8*)(Ab + (kt + 1) * 16384 + tid * 16);
#pragma unroll
      for (int j = 0; j < 8; ++j)
        gl_lds16(Bb + (size_t)(j >> 1) * 1048576 + (size_t)(kt + 1) * 16384 + (j & 1) * 8192 + tid * 16,
                 sBn + j * 8192 + tid * 16);
    }
    // ks = 0
    {
      h8 a[2], bbf[8];
#pragma unroll
      for (int rt = 0; rt < 2; ++rt) {
        const int r = rbase + rt * 16 + lr;
        a[rt] = *(const h8*)&sA[r * 64 + (((quad) ^ (lr & 7)) << 3)];
      }
#pragma unroll
      for (int ct = 0; ct < 8; ++ct) {
        const int d = cbase + ct * 16 + lr;
        bbf[ct] = *(const h8*)&sB[d * 64 + (((quad) ^ (lr & 7)) << 3)];
      }
      __builtin_amdgcn_s_setprio(1);
#pragma unroll
      for (int rt = 0; rt < 2; ++rt)
#pragma unroll
        for (int ct = 0; ct < 8; ++ct)
          acc[rt][ct] = MFMA16(a[rt], bbf[ct], acc[rt][ct]);
      __builtin_amdgcn_s_setprio(0);
    }
    // exp next-A while MFMA ks0 retires; write into next buf
    if (more) {
      h8 w;
#pragma unroll
      for (int u = 0; u < 8; ++u) { float e = __expf((float)han[u] - m0); w[u] = (_Float16)e; rs += e; }
      *(h8*)(sAn + tid * 16) = w;
    }
    // ks = 1
    {
      h8 a[2], bbf[8];
#pragma unroll
      for (int rt = 0; rt < 2; ++rt) {
        const int r = rbase + rt * 16 + lr;
        a[rt] = *(const h8*)&sA[r * 64 + (((4 | quad) ^ (lr & 7)) << 3)];
      }
#pragma unroll
      for (int ct = 0; ct < 8; ++ct) {
        const int d = cbase + ct * 16 + lr;
        bbf[ct] = *(const h8*)&sB[d * 64 + (((4 | quad) ^ (lr & 7)) << 3)];
      }
      __builtin_amdgcn_s_setprio(1);
#pragma unroll
      for (int rt = 0; rt < 2; ++rt)
#pragma unroll
        for (int ct = 0; ct < 8; ++ct)
          acc[rt][ct] = MFMA16(a[rt], bbf[ct], acc[rt][ct]);
      __builtin_amdgcn_s_setprio(0);
    }
    // next tile fully resident + this tile's readers/writers done
    asm volatile("s_waitcnt vmcnt(0) lgkmcnt(0)" ::: "memory");
    __builtin_amdgcn_s_barrier();
    __builtin_amdgcn_sched_barrier(0);
  }

  // rowsum: reduce across the 8 threads sharing each staged row, publish via LDS
  rs += __shfl_xor(rs, 1); rs += __shfl_xor(rs, 2); rs += __shfl_xor(rs, 4);
  if ((tid & 7) == 0) ls[lrow] = rs;
  __syncthreads();

  // epilogue: x 1/rowsum, scatter stores (64B segments per quad)
#pragma unroll
  for (int rt = 0; rt < 2; ++rt) {
#pragma unroll
    for (int r = 0; r < 4; ++r) {
      const int lrw = rbase + rt * 16 + quad * 4 + r;
      const int srow = s0 + yl * 64 + lrw;
      const float li = 1.0f / ls[lrw];
      float* op = &out[((size_t)b * 4096 + srow) * 512];
#pragma unroll
      for (int ct = 0; ct < 8; ++ct)
        op[cbase + ct * 16 + lr] = acc[rt][ct][r] * li;
    }
  }
}

extern "C" void kernel_launch(void* const* d_in, const int* in_sizes, int n_in,
                              void* d_out, int out_size, void* d_ws, size_t ws_size,
                              hipStream_t stream) {
  (void)in_sizes; (void)n_in; (void)out_size;
  const float* x  = (const float*)d_in[0];
  const float* Wq = (const float*)d_in[1];
  const float* bq = (const float*)d_in[2];
  const float* Wk = (const float*)d_in[3];
  const float* bk = (const float*)d_in[4];
  const float* Wv = (const float*)d_in[5];
  const float* bv = (const float*)d_in[6];
  float* out = (float*)d_out;
  char* ws = (char*)d_ws;
  char* Qimg  = ws;
  char* Kimg  = ws + ((size_t)16 << 20);
  char* VTimg = ws + ((size_t)32 << 20);
  _Float16* Wt = (_Float16*)(ws + ((size_t)48 << 20));            // 1.5MB
  unsigned* mEnc = (unsigned*)(ws + ((size_t)50 << 20) - 65536);  // 64KB row-max
  char* Simg   = ws + ((size_t)50 << 20);

  wconv_kernel<<<dim3(384), dim3(256), 0, stream>>>(Wq, Wk, Wv, Wt, mEnc);
  proj_kernel<<<dim3(128, 4, 3), dim3(256), 0, stream>>>(x, Wt, bq, bk, bv, Qimg, Kimg, VTimg);

  // chunk ladder on ws_size (constant per deployment -> same work every call)
  const size_t avail = ws_size > ((size_t)50 << 20) ? ws_size - ((size_t)50 << 20) : 0;
  int nchunk, nb, Ms;
  if      (avail >= ((size_t)128 << 20)) { nchunk = 1;  nb = 4; Ms = 4096; }
  else if (avail >= ((size_t)64  << 20)) { nchunk = 2;  nb = 2; Ms = 4096; }
  else if (avail >= ((size_t)32  << 20)) { nchunk = 4;  nb = 1; Ms = 4096; }
  else if (avail >= ((size_t)16  << 20)) { nchunk = 8;  nb = 1; Ms = 2048; }
  else if (avail >= ((size_t)8   << 20)) { nchunk = 16; nb = 1; Ms = 1024; }
  else                                   { nchunk = 32; nb = 1; Ms = 512;  }
  const int chunksPerBatch = 4096 / Ms;  // for nb==1 paths; nb>1 has Ms=4096
  const int nyb = Ms / 64;

  for (int c = 0; c < nchunk; ++c) {
    int b0, s0;
    if (nb > 1 || Ms == 4096) { b0 = c * nb; s0 = 0; }
    else { b0 = c / chunksPerBatch; s0 = (c % chunksPerBatch) * Ms; }
    qk_kernel<<<dim3(32, Ms / 128, nb), dim3(256), 0, stream>>>(Qimg, Kimg, Simg, mEnc, b0, s0);
    pv_kernel<<<dim3(nb * nyb), dim3(512), 0, stream>>>(Simg, VTimg, mEnc, out, b0, s0, nyb, nb);
  }
}